// Round 10
// baseline (209.760 us; speedup 1.0000x reference)
//
#include <hip/hip_runtime.h>

// MoE top-2 SwiGLU (fp32 in/out, fp16 MFMA internal).
// Dispatches: memset(counts) -> prep_k (route + cvt x + transpose w13 + w2) ->
// gemm1 (128x(64g+64u), BK=32, silu fused) -> gemm2 (128x128, BK=64).
// h_ws uses SORTED layout (row = rowbase[e] + m): gemm1 stores m-contiguous,
// gemm2 A-staging streams sequentially (scatter deferred to gemm2 C-write).
// Evidence log: gemm1 BK=64 regressed (67.2 vs 61.7 us); epilogue LDS-repack
// regressed (+1.7 us); n0-major grid regressed (69.6 us, FETCH 64->87 MB: A-gather
// sharing beats B-sharing -> keep n0-fastest grid); XOR seg swizzle on global
// side keeps SQ_LDS_BANK_CONFLICT == 0 with unpadded glds16 tiles.

#define H_DIM 512
#define I_DIM 1024
#define E_NUM 8
#define P_PAIRS 16384
#define CAP P_PAIRS
#define MAX_TILES 136   // sum ceil(ne/128) <= 16384/128 + 7 = 135

// prep_k block ranges
#define PREP_TW13 2048              // (2I/64=32) x (H/64=8) x E=8
#define PREP_TW2 1024               // (H/64=8) x (I/64=16) x E=8
#define PREP_CVT 2048               // 8192*512 / (256*8)
#define PREP_ROUTE 64               // 16384 / 256
#define PREP_BLOCKS (PREP_TW13 + PREP_TW2 + PREP_CVT + PREP_ROUTE)

typedef _Float16 half8 __attribute__((ext_vector_type(8)));
typedef float f32x4 __attribute__((ext_vector_type(4)));
typedef unsigned int u32;
typedef const __attribute__((address_space(1))) u32* gas_t;
typedef __attribute__((address_space(3))) u32* las_t;

__device__ __forceinline__ void glds16(const void* g, void* l) {
  __builtin_amdgcn_global_load_lds((gas_t)g, (las_t)l, 16, 0, 0);
}

// derive (e, m0, ne, rowbase) for compact tile id ty; false if ty OOB
__device__ __forceinline__ bool tile_decode(const int* counts, int ty, int& e,
                                            int& m0, int& ne, int& rb) {
  int base = 0;
  rb = 0;
  for (e = 0; e < E_NUM; ++e) {
    ne = counts[e];
    const int nt = (ne + 127) >> 7;
    if (ty < base + nt) { m0 = (ty - base) << 7; return true; }
    base += nt;
    rb += ne;
  }
  return false;
}

// ------------------------------------------------------------------- prep ---
__global__ __launch_bounds__(256) void prep_k(
    const float* __restrict__ x, const int* __restrict__ idx,
    const float* __restrict__ w13, const float* __restrict__ w2,
    int* __restrict__ counts, int* __restrict__ lists,
    _Float16* __restrict__ xh, _Float16* __restrict__ w13t,
    _Float16* __restrict__ w2t) {
  __shared__ __align__(16) _Float16 tile[64][72];  // 9216 B (route reuses head)
  const int b = blockIdx.x;
  const int tid = threadIdx.x;

  if (b < PREP_TW13 + PREP_TW2) {
    const float* src;
    _Float16* dst;
    int R, C, c0, r0;
    if (b < PREP_TW13) {
      R = H_DIM; C = 2 * I_DIM;
      const int e = b >> 8;
      c0 = (b & 31) * 64;
      r0 = ((b >> 5) & 7) * 64;
      src = w13 + (size_t)e * R * C;
      dst = w13t + (size_t)e * C * R;
    } else {
      const int l = b - PREP_TW13;
      R = I_DIM; C = H_DIM;
      const int e = l >> 7;
      c0 = (l & 7) * 64;
      r0 = ((l >> 3) & 15) * 64;
      src = w2 + (size_t)e * R * C;
      dst = w2t + (size_t)e * C * R;
    }
    {
      const int r = tid >> 4;
      const int c4 = (tid & 15) * 4;
      for (int pass = 0; pass < 4; ++pass) {
        f32x4 v = *(const f32x4*)(src + (size_t)(r0 + pass * 16 + r) * C + c0 + c4);
        for (int j = 0; j < 4; ++j) tile[c4 + j][pass * 16 + r] = (_Float16)v[j];
      }
    }
    __syncthreads();
    {
      const int c = tid >> 3;
      const int r8 = (tid & 7) * 8;
      for (int pass = 0; pass < 2; ++pass) {
        half8 h = *(const half8*)&tile[pass * 32 + c][r8];
        *(half8*)(dst + (size_t)(c0 + pass * 32 + c) * R + r0 + r8) = h;
      }
    }
  } else if (b < PREP_TW13 + PREP_TW2 + PREP_CVT) {
    const int l = b - (PREP_TW13 + PREP_TW2);
    const size_t i = ((size_t)l * 256 + tid) * 8;
    f32x4 v0 = *(const f32x4*)(x + i);
    f32x4 v1 = *(const f32x4*)(x + i + 4);
    half8 h;
    for (int j = 0; j < 4; ++j) { h[j] = (_Float16)v0[j]; h[j + 4] = (_Float16)v1[j]; }
    *(half8*)(xh + i) = h;
  } else {
    int* lcnt = (int*)&tile[0][0];
    int* lbase = lcnt + E_NUM;
    const int l = b - (PREP_TW13 + PREP_TW2 + PREP_CVT);
    if (tid < E_NUM) lcnt[tid] = 0;
    __syncthreads();
    const int p = l * 256 + tid;
    const int e = idx[p];
    const int r = atomicAdd(&lcnt[e], 1);
    __syncthreads();
    if (tid < E_NUM) lbase[tid] = atomicAdd(&counts[tid], lcnt[tid]);
    __syncthreads();
    lists[e * CAP + lbase[e] + r] = p;
  }
}

// ------------------------------------------------------------------ GEMM 1 ---
// Tile: 128 gathered pairs x (64 gate + 64 up cols), K=512, BK=32. 4 waves 2x2.
// Grid: x = n0 (fastest -> co-resident blocks share the A gather), y = m-tile.
// Output: sorted h_ws row rb + m0 + mrow.
__global__ __launch_bounds__(256) void gemm1_k(
    const _Float16* __restrict__ xh, const _Float16* __restrict__ w13t,
    const int* __restrict__ counts, const int* __restrict__ lists,
    _Float16* __restrict__ h_ws) {
  int e, m0, ne, rb;
  if (!tile_decode(counts, blockIdx.y, e, m0, ne, rb)) return;
  const int n0 = blockIdx.x * 64;

  __shared__ int rows[128];
  __shared__ __align__(16) _Float16 As[128 * 32];   // 8 KB
  __shared__ __align__(16) _Float16 Bgs[64 * 32];   // 4 KB
  __shared__ __align__(16) _Float16 Bus[64 * 32];   // 4 KB

  const int tid = threadIdx.x;
  if (tid < 128) {
    const int m = m0 + tid;
    rows[tid] = (m < ne) ? lists[e * CAP + m] : -1;
  }
  __syncthreads();

  // staging: row sr = tid/4, seg s4 = tid%4 (16B), XOR swizzle on global side
  const int sr = tid >> 2;
  const int s4 = tid & 3;
  const int segoff = ((s4 ^ ((sr >> 1) & 3)) * 8);
  const int pa0 = rows[sr];
  const int pa1 = rows[64 + sr];
  const int t0 = (pa0 >= 0) ? (pa0 >> 1) : 0;
  const int t1 = (pa1 >= 0) ? (pa1 >> 1) : 0;
  const _Float16* ga0 = xh + (size_t)t0 * H_DIM + segoff;
  const _Float16* ga1 = xh + (size_t)t1 * H_DIM + segoff;
  const _Float16* gbg = w13t + ((size_t)e * 2 * I_DIM + n0 + sr) * H_DIM + segoff;
  const _Float16* gbu = gbg + (size_t)I_DIM * H_DIM;
  _Float16* la0 = As + sr * 32 + s4 * 8;
  _Float16* la1 = As + (64 + sr) * 32 + s4 * 8;
  _Float16* lbg = Bgs + sr * 32 + s4 * 8;
  _Float16* lbu = Bus + sr * 32 + s4 * 8;

  const int lane = tid & 63;
  const int wid = tid >> 6;
  const int wm = wid & 1;
  const int wn = wid >> 1;
  const int fm = lane & 15;
  const int q = lane >> 4;
  int aoff[4], boff[2];
  for (int mi = 0; mi < 4; ++mi) {
    const int rA = wm * 64 + mi * 16 + fm;
    aoff[mi] = rA * 32 + ((q ^ ((rA >> 1) & 3)) * 8);
  }
  for (int ni = 0; ni < 2; ++ni) {
    const int cB = wn * 32 + ni * 16 + fm;
    boff[ni] = cB * 32 + ((q ^ ((cB >> 1) & 3)) * 8);
  }

  f32x4 accg[4][2] = {};
  f32x4 accu[4][2] = {};

  for (int k0 = 0; k0 < H_DIM; k0 += 32) {
    glds16(ga0 + k0, la0);
    glds16(ga1 + k0, la1);
    glds16(gbg + k0, lbg);
    glds16(gbu + k0, lbu);
    __syncthreads();

    half8 af[4], bg[2], bu[2];
    for (int mi = 0; mi < 4; ++mi) af[mi] = *(const half8*)&As[aoff[mi]];
    for (int ni = 0; ni < 2; ++ni) {
      bg[ni] = *(const half8*)&Bgs[boff[ni]];
      bu[ni] = *(const half8*)&Bus[boff[ni]];
    }
    for (int mi = 0; mi < 4; ++mi)
      for (int ni = 0; ni < 2; ++ni) {
        accg[mi][ni] = __builtin_amdgcn_mfma_f32_16x16x32_f16(af[mi], bg[ni], accg[mi][ni], 0, 0, 0);
        accu[mi][ni] = __builtin_amdgcn_mfma_f32_16x16x32_f16(af[mi], bu[ni], accu[mi][ni], 0, 0, 0);
      }
    __syncthreads();
  }

  // epilogue: C/D layout col=lane&15, row=q*4+reg; silu(g)*u -> sorted h_ws
  for (int mi = 0; mi < 4; ++mi)
    for (int r = 0; r < 4; ++r) {
      const int mrow = wm * 64 + mi * 16 + q * 4 + r;
      if (m0 + mrow >= ne) continue;
      _Float16* hrow = h_ws + (size_t)(rb + m0 + mrow) * I_DIM + n0;
      for (int ni = 0; ni < 2; ++ni) {
        const int c = wn * 32 + ni * 16 + fm;
        const float g = accg[mi][ni][r];
        const float u = accu[mi][ni][r];
        hrow[c] = (_Float16)(g / (1.0f + __expf(-g)) * u);
      }
    }
}

// ------------------------------------------------------------------ GEMM 2 ---
// Tile: 128 SEQUENTIAL sorted-h rows x 128 out cols, K=1024, BK=64. 4 waves 2x2.
// Grid: x = n0 (fastest), y = m-tile. Scatter only at C-write via rows[].
__global__ __launch_bounds__(256) void gemm2_k(
    const _Float16* __restrict__ h_ws, const _Float16* __restrict__ w2t,
    const int* __restrict__ counts, const int* __restrict__ lists,
    float* __restrict__ out) {
  int e, m0, ne, rb;
  if (!tile_decode(counts, blockIdx.y, e, m0, ne, rb)) return;
  const int n0 = blockIdx.x * 128;

  __shared__ int rows[128];
  __shared__ __align__(16) _Float16 As[128 * 64];  // 16 KB
  __shared__ __align__(16) _Float16 Bs[128 * 64];  // 16 KB

  const int tid = threadIdx.x;
  if (tid < 128) {
    const int m = m0 + tid;
    rows[tid] = (m < ne) ? lists[e * CAP + m] : -1;
  }
  // no barrier needed: rows[] first read in epilogue, loop barriers cover it

  const int s8 = tid & 7;
  const int sr8 = tid >> 3;
  const int sw = ((s8 ^ (sr8 & 7)) * 8);
  const _Float16* gA[4];
  const _Float16* gB[4];
  _Float16* lA[4];
  _Float16* lB[4];
  for (int pa = 0; pa < 4; ++pa) {
    const int m = pa * 32 + sr8;
    gA[pa] = h_ws + (size_t)(rb + m0 + m) * I_DIM + sw;  // sequential rows
    lA[pa] = As + m * 64 + s8 * 8;
    gB[pa] = w2t + ((size_t)e * H_DIM + n0 + m) * I_DIM + sw;
    lB[pa] = Bs + m * 64 + s8 * 8;
  }

  const int lane = tid & 63;
  const int wid = tid >> 6;
  const int wm = wid & 1;
  const int wn = wid >> 1;
  const int fm = lane & 15;
  const int q = lane >> 4;
  int aoff[2][4], boff[2][4];
  for (int ks = 0; ks < 2; ++ks) {
    for (int mi = 0; mi < 4; ++mi) {
      const int rA = wm * 64 + mi * 16 + fm;
      aoff[ks][mi] = rA * 64 + (((ks * 4 + q) ^ (rA & 7)) * 8);
    }
    for (int ni = 0; ni < 4; ++ni) {
      const int cB = wn * 64 + ni * 16 + fm;
      boff[ks][ni] = cB * 64 + (((ks * 4 + q) ^ (cB & 7)) * 8);
    }
  }

  f32x4 acc[4][4] = {};

  for (int k0 = 0; k0 < I_DIM; k0 += 64) {
    for (int pa = 0; pa < 4; ++pa) {
      glds16(gA[pa] + k0, lA[pa]);
      glds16(gB[pa] + k0, lB[pa]);
    }
    __syncthreads();

    for (int ks = 0; ks < 2; ++ks) {
      half8 af[4], bf[4];
      for (int mi = 0; mi < 4; ++mi) af[mi] = *(const half8*)&As[aoff[ks][mi]];
      for (int ni = 0; ni < 4; ++ni) bf[ni] = *(const half8*)&Bs[boff[ks][ni]];
      for (int mi = 0; mi < 4; ++mi)
        for (int ni = 0; ni < 4; ++ni)
          acc[mi][ni] = __builtin_amdgcn_mfma_f32_16x16x32_f16(af[mi], bf[ni], acc[mi][ni], 0, 0, 0);
    }
    __syncthreads();
  }

  for (int mi = 0; mi < 4; ++mi)
    for (int r = 0; r < 4; ++r) {
      const int mrow = wm * 64 + mi * 16 + q * 4 + r;
      const int p = rows[mrow];
      if (p < 0) continue;
      float* orow = out + (size_t)p * H_DIM + n0;
      for (int ni = 0; ni < 4; ++ni)
        orow[wn * 64 + ni * 16 + fm] = acc[mi][ni][r];
    }
}

// ------------------------------------------------------------------ launch ---
extern "C" void kernel_launch(void* const* d_in, const int* in_sizes, int n_in,
                              void* d_out, int out_size, void* d_ws, size_t ws_size,
                              hipStream_t stream) {
  const float* x = (const float*)d_in[0];
  const int* idx = (const int*)d_in[1];
  const float* w13 = (const float*)d_in[2];
  const float* w2 = (const float*)d_in[3];

  char* ws = (char*)d_ws;
  int* counts = (int*)ws;                  // 8 ints (pad to 2048)
  int* lists = (int*)(ws + 2048);          // 512 KB
  const size_t OFF_XH = 2048 + (size_t)E_NUM * CAP * 4;
  const size_t OFF_W13T = OFF_XH + (size_t)P_PAIRS / 2 * H_DIM * 2;          // +8.39 MB
  const size_t OFF_W2T = OFF_W13T + (size_t)E_NUM * 2 * I_DIM * H_DIM * 2;   // +16.78 MB
  const size_t OFF_H = OFF_W2T + (size_t)E_NUM * H_DIM * I_DIM * 2;          // +8.39 MB
  _Float16* xh = (_Float16*)(ws + OFF_XH);     // [B*S][H] fp16
  _Float16* w13t = (_Float16*)(ws + OFF_W13T); // [E][2I][H] fp16
  _Float16* w2t = (_Float16*)(ws + OFF_W2T);   // [E][H][I]  fp16
  _Float16* h_ws = (_Float16*)(ws + OFF_H);    // [P][I] fp16, SORTED rows (33.5 MB)

  hipMemsetAsync(d_ws, 0, 128, stream);  // zero expert counts
  prep_k<<<dim3(PREP_BLOCKS), 256, 0, stream>>>(x, idx, w13, w2, counts, lists,
                                                xh, w13t, w2t);
  gemm1_k<<<dim3(I_DIM / 64, MAX_TILES), 256, 0, stream>>>(
      xh, w13t, counts, lists, h_ws);
  gemm2_k<<<dim3(H_DIM / 128, MAX_TILES), 256, 0, stream>>>(
      h_ws, w2t, counts, lists, (float*)d_out);
}

// Round 11
// 201.338 us; speedup vs baseline: 1.0418x; 1.0418x over previous
//
#include <hip/hip_runtime.h>

// MoE top-2 SwiGLU (fp32 in/out, fp16 MFMA internal).
// Dispatches: memset(counts) -> prep_k (route + cvt x + transpose w13 + w2) ->
// gemm1 (128x(64g+64u), BK=32, silu fused) -> gemm2 (128x128, BK=64).
// h_ws uses SORTED layout (row = rowbase[e] + m): gemm1 stores m-contiguous,
// gemm2 A-staging streams sequentially (scatter deferred to gemm2 C-write).
// Grid orders are PER-GEMM (measured):
//   gemm1: n0-fastest (x=n0,y=mtile) — shares the random A-gather; m-fastest
//          regressed 60->69.6 us w/ FETCH 64->87 MB (R9).
//   gemm2: m-fastest (x=mtile,y=n0) — R9 vs R8/R10 totals show ~16 us gain.
// Other evidence: gemm1 BK=64 regressed (67.2 vs 61.7); epilogue LDS-repack
// regressed (+1.7); XOR seg swizzle on global side keeps
// SQ_LDS_BANK_CONFLICT == 0 with unpadded glds16 tiles.

#define H_DIM 512
#define I_DIM 1024
#define E_NUM 8
#define P_PAIRS 16384
#define CAP P_PAIRS
#define MAX_TILES 136   // sum ceil(ne/128) <= 16384/128 + 7 = 135

// prep_k block ranges
#define PREP_TW13 2048              // (2I/64=32) x (H/64=8) x E=8
#define PREP_TW2 1024               // (H/64=8) x (I/64=16) x E=8
#define PREP_CVT 2048               // 8192*512 / (256*8)
#define PREP_ROUTE 64               // 16384 / 256
#define PREP_BLOCKS (PREP_TW13 + PREP_TW2 + PREP_CVT + PREP_ROUTE)

typedef _Float16 half8 __attribute__((ext_vector_type(8)));
typedef float f32x4 __attribute__((ext_vector_type(4)));
typedef unsigned int u32;
typedef const __attribute__((address_space(1))) u32* gas_t;
typedef __attribute__((address_space(3))) u32* las_t;

__device__ __forceinline__ void glds16(const void* g, void* l) {
  __builtin_amdgcn_global_load_lds((gas_t)g, (las_t)l, 16, 0, 0);
}

// derive (e, m0, ne, rowbase) for compact tile id ty; false if ty OOB
__device__ __forceinline__ bool tile_decode(const int* counts, int ty, int& e,
                                            int& m0, int& ne, int& rb) {
  int base = 0;
  rb = 0;
  for (e = 0; e < E_NUM; ++e) {
    ne = counts[e];
    const int nt = (ne + 127) >> 7;
    if (ty < base + nt) { m0 = (ty - base) << 7; return true; }
    base += nt;
    rb += ne;
  }
  return false;
}

// ------------------------------------------------------------------- prep ---
__global__ __launch_bounds__(256) void prep_k(
    const float* __restrict__ x, const int* __restrict__ idx,
    const float* __restrict__ w13, const float* __restrict__ w2,
    int* __restrict__ counts, int* __restrict__ lists,
    _Float16* __restrict__ xh, _Float16* __restrict__ w13t,
    _Float16* __restrict__ w2t) {
  __shared__ __align__(16) _Float16 tile[64][72];  // 9216 B (route reuses head)
  const int b = blockIdx.x;
  const int tid = threadIdx.x;

  if (b < PREP_TW13 + PREP_TW2) {
    const float* src;
    _Float16* dst;
    int R, C, c0, r0;
    if (b < PREP_TW13) {
      R = H_DIM; C = 2 * I_DIM;
      const int e = b >> 8;
      c0 = (b & 31) * 64;
      r0 = ((b >> 5) & 7) * 64;
      src = w13 + (size_t)e * R * C;
      dst = w13t + (size_t)e * C * R;
    } else {
      const int l = b - PREP_TW13;
      R = I_DIM; C = H_DIM;
      const int e = l >> 7;
      c0 = (l & 7) * 64;
      r0 = ((l >> 3) & 15) * 64;
      src = w2 + (size_t)e * R * C;
      dst = w2t + (size_t)e * C * R;
    }
    {
      const int r = tid >> 4;
      const int c4 = (tid & 15) * 4;
      for (int pass = 0; pass < 4; ++pass) {
        f32x4 v = *(const f32x4*)(src + (size_t)(r0 + pass * 16 + r) * C + c0 + c4);
        for (int j = 0; j < 4; ++j) tile[c4 + j][pass * 16 + r] = (_Float16)v[j];
      }
    }
    __syncthreads();
    {
      const int c = tid >> 3;
      const int r8 = (tid & 7) * 8;
      for (int pass = 0; pass < 2; ++pass) {
        half8 h = *(const half8*)&tile[pass * 32 + c][r8];
        *(half8*)(dst + (size_t)(c0 + pass * 32 + c) * R + r0 + r8) = h;
      }
    }
  } else if (b < PREP_TW13 + PREP_TW2 + PREP_CVT) {
    const int l = b - (PREP_TW13 + PREP_TW2);
    const size_t i = ((size_t)l * 256 + tid) * 8;
    f32x4 v0 = *(const f32x4*)(x + i);
    f32x4 v1 = *(const f32x4*)(x + i + 4);
    half8 h;
    for (int j = 0; j < 4; ++j) { h[j] = (_Float16)v0[j]; h[j + 4] = (_Float16)v1[j]; }
    *(half8*)(xh + i) = h;
  } else {
    int* lcnt = (int*)&tile[0][0];
    int* lbase = lcnt + E_NUM;
    const int l = b - (PREP_TW13 + PREP_TW2 + PREP_CVT);
    if (tid < E_NUM) lcnt[tid] = 0;
    __syncthreads();
    const int p = l * 256 + tid;
    const int e = idx[p];
    const int r = atomicAdd(&lcnt[e], 1);
    __syncthreads();
    if (tid < E_NUM) lbase[tid] = atomicAdd(&counts[tid], lcnt[tid]);
    __syncthreads();
    lists[e * CAP + lbase[e] + r] = p;
  }
}

// ------------------------------------------------------------------ GEMM 1 ---
// Tile: 128 gathered pairs x (64 gate + 64 up cols), K=512, BK=32. 4 waves 2x2.
// Grid: x = n0 (fastest -> co-resident blocks share the A gather), y = m-tile.
// Output: sorted h_ws row rb + m0 + mrow.
__global__ __launch_bounds__(256) void gemm1_k(
    const _Float16* __restrict__ xh, const _Float16* __restrict__ w13t,
    const int* __restrict__ counts, const int* __restrict__ lists,
    _Float16* __restrict__ h_ws) {
  int e, m0, ne, rb;
  if (!tile_decode(counts, blockIdx.y, e, m0, ne, rb)) return;
  const int n0 = blockIdx.x * 64;

  __shared__ int rows[128];
  __shared__ __align__(16) _Float16 As[128 * 32];   // 8 KB
  __shared__ __align__(16) _Float16 Bgs[64 * 32];   // 4 KB
  __shared__ __align__(16) _Float16 Bus[64 * 32];   // 4 KB

  const int tid = threadIdx.x;
  if (tid < 128) {
    const int m = m0 + tid;
    rows[tid] = (m < ne) ? lists[e * CAP + m] : -1;
  }
  __syncthreads();

  // staging: row sr = tid/4, seg s4 = tid%4 (16B), XOR swizzle on global side
  const int sr = tid >> 2;
  const int s4 = tid & 3;
  const int segoff = ((s4 ^ ((sr >> 1) & 3)) * 8);
  const int pa0 = rows[sr];
  const int pa1 = rows[64 + sr];
  const int t0 = (pa0 >= 0) ? (pa0 >> 1) : 0;
  const int t1 = (pa1 >= 0) ? (pa1 >> 1) : 0;
  const _Float16* ga0 = xh + (size_t)t0 * H_DIM + segoff;
  const _Float16* ga1 = xh + (size_t)t1 * H_DIM + segoff;
  const _Float16* gbg = w13t + ((size_t)e * 2 * I_DIM + n0 + sr) * H_DIM + segoff;
  const _Float16* gbu = gbg + (size_t)I_DIM * H_DIM;
  _Float16* la0 = As + sr * 32 + s4 * 8;
  _Float16* la1 = As + (64 + sr) * 32 + s4 * 8;
  _Float16* lbg = Bgs + sr * 32 + s4 * 8;
  _Float16* lbu = Bus + sr * 32 + s4 * 8;

  const int lane = tid & 63;
  const int wid = tid >> 6;
  const int wm = wid & 1;
  const int wn = wid >> 1;
  const int fm = lane & 15;
  const int q = lane >> 4;
  int aoff[4], boff[2];
  for (int mi = 0; mi < 4; ++mi) {
    const int rA = wm * 64 + mi * 16 + fm;
    aoff[mi] = rA * 32 + ((q ^ ((rA >> 1) & 3)) * 8);
  }
  for (int ni = 0; ni < 2; ++ni) {
    const int cB = wn * 32 + ni * 16 + fm;
    boff[ni] = cB * 32 + ((q ^ ((cB >> 1) & 3)) * 8);
  }

  f32x4 accg[4][2] = {};
  f32x4 accu[4][2] = {};

  for (int k0 = 0; k0 < H_DIM; k0 += 32) {
    glds16(ga0 + k0, la0);
    glds16(ga1 + k0, la1);
    glds16(gbg + k0, lbg);
    glds16(gbu + k0, lbu);
    __syncthreads();

    half8 af[4], bg[2], bu[2];
    for (int mi = 0; mi < 4; ++mi) af[mi] = *(const half8*)&As[aoff[mi]];
    for (int ni = 0; ni < 2; ++ni) {
      bg[ni] = *(const half8*)&Bgs[boff[ni]];
      bu[ni] = *(const half8*)&Bus[boff[ni]];
    }
    for (int mi = 0; mi < 4; ++mi)
      for (int ni = 0; ni < 2; ++ni) {
        accg[mi][ni] = __builtin_amdgcn_mfma_f32_16x16x32_f16(af[mi], bg[ni], accg[mi][ni], 0, 0, 0);
        accu[mi][ni] = __builtin_amdgcn_mfma_f32_16x16x32_f16(af[mi], bu[ni], accu[mi][ni], 0, 0, 0);
      }
    __syncthreads();
  }

  // epilogue: C/D layout col=lane&15, row=q*4+reg; silu(g)*u -> sorted h_ws
  for (int mi = 0; mi < 4; ++mi)
    for (int r = 0; r < 4; ++r) {
      const int mrow = wm * 64 + mi * 16 + q * 4 + r;
      if (m0 + mrow >= ne) continue;
      _Float16* hrow = h_ws + (size_t)(rb + m0 + mrow) * I_DIM + n0;
      for (int ni = 0; ni < 2; ++ni) {
        const int c = wn * 32 + ni * 16 + fm;
        const float g = accg[mi][ni][r];
        const float u = accu[mi][ni][r];
        hrow[c] = (_Float16)(g / (1.0f + __expf(-g)) * u);
      }
    }
}

// ------------------------------------------------------------------ GEMM 2 ---
// Tile: 128 SEQUENTIAL sorted-h rows x 128 out cols, K=1024, BK=64. 4 waves 2x2.
// Grid: x = m-tile (fastest), y = n0  [R9 evidence: ~16 us faster than n0-fastest].
__global__ __launch_bounds__(256) void gemm2_k(
    const _Float16* __restrict__ h_ws, const _Float16* __restrict__ w2t,
    const int* __restrict__ counts, const int* __restrict__ lists,
    float* __restrict__ out) {
  int e, m0, ne, rb;
  if (!tile_decode(counts, blockIdx.x, e, m0, ne, rb)) return;
  const int n0 = blockIdx.y * 128;

  __shared__ int rows[128];
  __shared__ __align__(16) _Float16 As[128 * 64];  // 16 KB
  __shared__ __align__(16) _Float16 Bs[128 * 64];  // 16 KB

  const int tid = threadIdx.x;
  if (tid < 128) {
    const int m = m0 + tid;
    rows[tid] = (m < ne) ? lists[e * CAP + m] : -1;
  }
  // no barrier needed: rows[] first read in epilogue, loop barriers cover it

  const int s8 = tid & 7;
  const int sr8 = tid >> 3;
  const int sw = ((s8 ^ (sr8 & 7)) * 8);
  const _Float16* gA[4];
  const _Float16* gB[4];
  _Float16* lA[4];
  _Float16* lB[4];
  for (int pa = 0; pa < 4; ++pa) {
    const int m = pa * 32 + sr8;
    gA[pa] = h_ws + (size_t)(rb + m0 + m) * I_DIM + sw;  // sequential rows
    lA[pa] = As + m * 64 + s8 * 8;
    gB[pa] = w2t + ((size_t)e * H_DIM + n0 + m) * I_DIM + sw;
    lB[pa] = Bs + m * 64 + s8 * 8;
  }

  const int lane = tid & 63;
  const int wid = tid >> 6;
  const int wm = wid & 1;
  const int wn = wid >> 1;
  const int fm = lane & 15;
  const int q = lane >> 4;
  int aoff[2][4], boff[2][4];
  for (int ks = 0; ks < 2; ++ks) {
    for (int mi = 0; mi < 4; ++mi) {
      const int rA = wm * 64 + mi * 16 + fm;
      aoff[ks][mi] = rA * 64 + (((ks * 4 + q) ^ (rA & 7)) * 8);
    }
    for (int ni = 0; ni < 4; ++ni) {
      const int cB = wn * 64 + ni * 16 + fm;
      boff[ks][ni] = cB * 64 + (((ks * 4 + q) ^ (cB & 7)) * 8);
    }
  }

  f32x4 acc[4][4] = {};

  for (int k0 = 0; k0 < I_DIM; k0 += 64) {
    for (int pa = 0; pa < 4; ++pa) {
      glds16(gA[pa] + k0, lA[pa]);
      glds16(gB[pa] + k0, lB[pa]);
    }
    __syncthreads();

    for (int ks = 0; ks < 2; ++ks) {
      half8 af[4], bf[4];
      for (int mi = 0; mi < 4; ++mi) af[mi] = *(const half8*)&As[aoff[ks][mi]];
      for (int ni = 0; ni < 4; ++ni) bf[ni] = *(const half8*)&Bs[boff[ks][ni]];
      for (int mi = 0; mi < 4; ++mi)
        for (int ni = 0; ni < 4; ++ni)
          acc[mi][ni] = __builtin_amdgcn_mfma_f32_16x16x32_f16(af[mi], bf[ni], acc[mi][ni], 0, 0, 0);
    }
    __syncthreads();
  }

  for (int mi = 0; mi < 4; ++mi)
    for (int r = 0; r < 4; ++r) {
      const int mrow = wm * 64 + mi * 16 + q * 4 + r;
      const int p = rows[mrow];
      if (p < 0) continue;
      float* orow = out + (size_t)p * H_DIM + n0;
      for (int ni = 0; ni < 4; ++ni)
        orow[wn * 64 + ni * 16 + fm] = acc[mi][ni][r];
    }
}

// ------------------------------------------------------------------ launch ---
extern "C" void kernel_launch(void* const* d_in, const int* in_sizes, int n_in,
                              void* d_out, int out_size, void* d_ws, size_t ws_size,
                              hipStream_t stream) {
  const float* x = (const float*)d_in[0];
  const int* idx = (const int*)d_in[1];
  const float* w13 = (const float*)d_in[2];
  const float* w2 = (const float*)d_in[3];

  char* ws = (char*)d_ws;
  int* counts = (int*)ws;                  // 8 ints (pad to 2048)
  int* lists = (int*)(ws + 2048);          // 512 KB
  const size_t OFF_XH = 2048 + (size_t)E_NUM * CAP * 4;
  const size_t OFF_W13T = OFF_XH + (size_t)P_PAIRS / 2 * H_DIM * 2;          // +8.39 MB
  const size_t OFF_W2T = OFF_W13T + (size_t)E_NUM * 2 * I_DIM * H_DIM * 2;   // +16.78 MB
  const size_t OFF_H = OFF_W2T + (size_t)E_NUM * H_DIM * I_DIM * 2;          // +8.39 MB
  _Float16* xh = (_Float16*)(ws + OFF_XH);     // [B*S][H] fp16
  _Float16* w13t = (_Float16*)(ws + OFF_W13T); // [E][2I][H] fp16
  _Float16* w2t = (_Float16*)(ws + OFF_W2T);   // [E][H][I]  fp16
  _Float16* h_ws = (_Float16*)(ws + OFF_H);    // [P][I] fp16, SORTED rows (33.5 MB)

  hipMemsetAsync(d_ws, 0, 128, stream);  // zero expert counts
  prep_k<<<dim3(PREP_BLOCKS), 256, 0, stream>>>(x, idx, w13, w2, counts, lists,
                                                xh, w13t, w2t);
  gemm1_k<<<dim3(I_DIM / 64, MAX_TILES), 256, 0, stream>>>(
      xh, w13t, counts, lists, h_ws);
  gemm2_k<<<dim3(MAX_TILES, H_DIM / 128), 256, 0, stream>>>(
      h_ws, w2t, counts, lists, (float*)d_out);
}